// Round 3
// baseline (314.240 us; speedup 1.0000x reference)
//
#include <hip/hip_runtime.h>
#include <hip/hip_bf16.h>
#include <math.h>

#define NPTS 100000
#define KOFF 27

typedef __attribute__((ext_vector_type(8))) __bf16 bf16x8;
typedef __attribute__((ext_vector_type(4))) float f32x4;

__device__ __forceinline__ unsigned short f2bf(float f) {
    unsigned int u = __float_as_uint(f);
    u += 0x7fffu + ((u >> 16) & 1u);   // RNE
    return (unsigned short)(u >> 16);
}

__device__ __forceinline__ float gelu_erf(float v) {
    return 0.5f * v * (1.0f + erff(v * 0.70710678118654752f));
}

// ---------------------------------------------------------------------------
// Kernel 0: repack W1/W2 (fp32 -> bf16) into per-lane MFMA B-fragment order,
// sniff mask dtype, and zero the sentinel rows (row NPTS) of out0/out1.
// ---------------------------------------------------------------------------
__global__ __launch_bounds__(256)
void repack_kernel(const float* __restrict__ W1, const float* __restrict__ W2,
                   const void* __restrict__ maskp,
                   unsigned short* __restrict__ W1p,
                   unsigned short* __restrict__ W2p,
                   int* __restrict__ flagp,
                   unsigned short* __restrict__ out0,
                   unsigned short* __restrict__ out1) {
    int o = blockIdx.x * 256 + threadIdx.x;
    if (blockIdx.x == 0) {
        int t = threadIdx.x;
        if (t == 0) {
            const unsigned int* mw = (const unsigned int*)maskp;
            int f = 0;
            for (int i = 0; i < 64; ++i) f |= (mw[i] > 1u) ? 1 : 0;
            *flagp = f;   // 1 => byte/bool mask, 0 => int32 mask
        }
        if (t < 32)  out0[NPTS * 32 + t] = 0;     // sentinel zero row
        if (t < 128) out1[NPTS * 128 + t] = 0;    // sentinel zero row
    }
    if (o < KOFF * 32 * 128) {
        int j = o & 7, lane = (o >> 3) & 63;
        int quad = lane >> 4, nn = lane & 15;
        int ct1 = (o >> 9) & 7, k1 = o >> 12;
        int kk1 = quad * 8 + j;
        W1p[o] = f2bf(W1[(k1 * 32 + kk1) * 128 + (ct1 * 16 + nn)]);
        int ct2 = (o >> 9) & 1, kc2 = (o >> 10) & 3, k2 = o >> 12;
        int kk2 = kc2 * 32 + quad * 8 + j;
        W2p[o] = f2bf(W2[(k2 * 128 + kk2) * 32 + (ct2 * 16 + nn)]);
    }
}

// ---------------------------------------------------------------------------
// Kernel 1: out0 = bf16( gelu( LN( x @ W_conv ) ) )   [N,32]
// ---------------------------------------------------------------------------
__global__ __launch_bounds__(256)
void conv1_ln_gelu(const float* __restrict__ x, const float* __restrict__ Wc,
                   const float* __restrict__ g0, const float* __restrict__ b0,
                   unsigned short* __restrict__ out0) {
    __shared__ float xs[256];
    __shared__ float wc[1024];
    int t = threadIdx.x;
    int nb = blockIdx.x * 8;
    xs[t] = x[nb * 32 + t];
    for (int i = t; i < 1024; i += 256) wc[i] = Wc[i];
    __syncthreads();
    int r = t >> 5, d = t & 31;
    const float* xr = &xs[r * 32];
    float v = 0.f;
#pragma unroll
    for (int c = 0; c < 32; ++c) v = fmaf(xr[c], wc[c * 32 + d], v);
    float s = v, s2 = v * v;
#pragma unroll
    for (int m = 16; m >= 1; m >>= 1) {
        s  += __shfl_xor(s,  m, 32);
        s2 += __shfl_xor(s2, m, 32);
    }
    float mu  = s * (1.f / 32.f);
    float var = s2 * (1.f / 32.f) - mu * mu;
    float y = (v - mu) * rsqrtf(var + 1e-6f) * g0[d] + b0[d];
    out0[nb * 32 + t] = f2bf(gelu_erf(y));
}

// ---------------------------------------------------------------------------
// Stage gather indices for 64 rows into LDS; masked/tail -> NPTS (zero row)
// ---------------------------------------------------------------------------
__device__ __forceinline__ void stage_gidx(int* s_gidx, const int* nidx,
                                           const void* maskp, int mflag,
                                           int nb, int t) {
    int cnt = (NPTS - nb < 64 ? NPTS - nb : 64) * KOFF;
    for (int i = t; i < 64 * KOFF; i += 256) {
        int g = NPTS;
        if (i < cnt) {
            int gi = nidx[nb * KOFF + i];
            int m = mflag ? (int)((const unsigned char*)maskp)[nb * KOFF + i]
                          : ((const int*)maskp)[nb * KOFF + i];
            g = m ? gi : NPTS;
        }
        s_gidx[i] = g;
    }
}

// ---------------------------------------------------------------------------
// Kernel 2: out1 = bf16( gelu( LN( sparse_conv(out0, W1) ) ) )   [N,128]
// Wave w owns row-tile w; 8 col-tiles; branch-free gathers, prefetch depth 6.
// ---------------------------------------------------------------------------
__global__ __launch_bounds__(256, 4)
void conv_k1(const int* __restrict__ nidx, const void* __restrict__ maskp,
             const int* __restrict__ flagp,
             const unsigned short* __restrict__ out0,
             const unsigned short* __restrict__ W1p,
             const float* __restrict__ g1, const float* __restrict__ b1,
             unsigned short* __restrict__ out1) {
    __shared__ int   s_gidx[64 * KOFF];
    __shared__ float s_g[128], s_b[128];

    int t = threadIdx.x;
    int nb = blockIdx.x * 64;
    int mflag = *flagp;
    if (t < 128) { s_g[t] = g1[t]; s_b[t] = b1[t]; }
    stage_gidx(s_gidx, nidx, maskp, mflag, nb, t);
    __syncthreads();

    int lane = t & 63, w = t >> 6;
    int mrow = lane & 15, quad = lane >> 4;
    const int* gp = &s_gidx[(w * 16 + mrow) * KOFF];
    const unsigned short* a_base = out0 + quad * 8;

    f32x4 acc[8] = {};
    bf16x8 a_pf[6];
#pragma unroll
    for (int d = 0; d < 6; ++d)
        a_pf[d] = *reinterpret_cast<const bf16x8*>(a_base + gp[d] * 32);

#pragma unroll
    for (int k = 0; k < KOFF; ++k) {
        const unsigned short* wb = W1p + (((k * 8) * 64 + lane) << 3);
#pragma unroll
        for (int ct = 0; ct < 8; ++ct) {
            bf16x8 bfr = *reinterpret_cast<const bf16x8*>(wb + ((ct * 64) << 3));
            acc[ct] = __builtin_amdgcn_mfma_f32_16x16x32_bf16(a_pf[k % 6], bfr, acc[ct], 0, 0, 0);
        }
        int kn = (k + 6 < KOFF) ? k + 6 : KOFF - 1;
        a_pf[k % 6] = *reinterpret_cast<const bf16x8*>(a_base + gp[kn] * 32);
    }

    // Epilogue: LN(128) + GELU in-register.
    int n_base = nb + w * 16 + quad * 4;
#pragma unroll
    for (int r = 0; r < 4; ++r) {
        float s = 0.f, s2 = 0.f;
#pragma unroll
        for (int ct = 0; ct < 8; ++ct) { float v = acc[ct][r]; s += v; s2 += v * v; }
#pragma unroll
        for (int m = 1; m <= 8; m <<= 1) {
            s  += __shfl_xor(s,  m, 16);
            s2 += __shfl_xor(s2, m, 16);
        }
        float mu = s * (1.f / 128.f);
        float rs = rsqrtf(s2 * (1.f / 128.f) - mu * mu + 1e-6f);
        int n = n_base + r;
        if (n < NPTS) {
#pragma unroll
            for (int ct = 0; ct < 8; ++ct) {
                int c = ct * 16 + mrow;
                float y = (acc[ct][r] - mu) * rs * s_g[c] + s_b[c];
                out1[n * 128 + c] = f2bf(gelu_erf(y));
            }
        }
    }
}

// ---------------------------------------------------------------------------
// Kernel 3: out = gelu( LN( sparse_conv(out1, W2) ) + x )   [N,32] fp32
// Wave w owns row-tile w; branch-free gathers (zero row), prefetch depth 4.
// ---------------------------------------------------------------------------
__global__ __launch_bounds__(256, 4)
void conv_k2(const int* __restrict__ nidx, const void* __restrict__ maskp,
             const int* __restrict__ flagp,
             const unsigned short* __restrict__ out1,
             const unsigned short* __restrict__ W2p,
             const float* __restrict__ g2, const float* __restrict__ b2,
             const float* __restrict__ x, float* __restrict__ outp) {
    __shared__ int   s_gidx[64 * KOFF];
    __shared__ float s_g[32], s_b[32];

    int t = threadIdx.x;
    int nb = blockIdx.x * 64;
    int mflag = *flagp;
    if (t < 32) { s_g[t] = g2[t]; s_b[t] = b2[t]; }
    stage_gidx(s_gidx, nidx, maskp, mflag, nb, t);
    __syncthreads();

    int lane = t & 63, w = t >> 6;
    int mrow = lane & 15, quad = lane >> 4;
    const int* gp = &s_gidx[(w * 16 + mrow) * KOFF];
    const unsigned short* a_base = out1 + quad * 8;

    f32x4 acc[2] = {};
    bf16x8 a_pf[4][4];
#pragma unroll
    for (int d = 0; d < 4; ++d) {
        int g = gp[d];
#pragma unroll
        for (int kc = 0; kc < 4; ++kc)
            a_pf[d][kc] = *reinterpret_cast<const bf16x8*>(a_base + g * 128 + kc * 32);
    }

#pragma unroll
    for (int k = 0; k < KOFF; ++k) {
        const unsigned short* wb = W2p + (((k * 8) * 64 + lane) << 3);
#pragma unroll
        for (int kc = 0; kc < 4; ++kc) {
            bf16x8 b0 = *reinterpret_cast<const bf16x8*>(wb + (((kc * 2 + 0) * 64) << 3));
            bf16x8 b1 = *reinterpret_cast<const bf16x8*>(wb + (((kc * 2 + 1) * 64) << 3));
            acc[0] = __builtin_amdgcn_mfma_f32_16x16x32_bf16(a_pf[k % 4][kc], b0, acc[0], 0, 0, 0);
            acc[1] = __builtin_amdgcn_mfma_f32_16x16x32_bf16(a_pf[k % 4][kc], b1, acc[1], 0, 0, 0);
        }
        int kn = (k + 4 < KOFF) ? k + 4 : KOFF - 1;
        int g = gp[kn];
#pragma unroll
        for (int kc = 0; kc < 4; ++kc)
            a_pf[k % 4][kc] = *reinterpret_cast<const bf16x8*>(a_base + g * 128 + kc * 32);
    }

    // Epilogue: LN(32) + residual + GELU in-register.
    int n_base = nb + w * 16 + quad * 4;
#pragma unroll
    for (int r = 0; r < 4; ++r) {
        float v0 = acc[0][r], v1 = acc[1][r];
        float s = v0 + v1, s2 = v0 * v0 + v1 * v1;
#pragma unroll
        for (int m = 1; m <= 8; m <<= 1) {
            s  += __shfl_xor(s,  m, 16);
            s2 += __shfl_xor(s2, m, 16);
        }
        float mu = s * (1.f / 32.f);
        float rs = rsqrtf(s2 * (1.f / 32.f) - mu * mu + 1e-6f);
        int n = n_base + r;
        if (n < NPTS) {
            int c0 = mrow, c1 = mrow + 16;
            float y0 = (v0 - mu) * rs * s_g[c0] + s_b[c0] + x[n * 32 + c0];
            float y1 = (v1 - mu) * rs * s_g[c1] + s_b[c1] + x[n * 32 + c1];
            outp[n * 32 + c0] = gelu_erf(y0);
            outp[n * 32 + c1] = gelu_erf(y1);
        }
    }
}

// ---------------------------------------------------------------------------
extern "C" void kernel_launch(void* const* d_in, const int* in_sizes, int n_in,
                              void* d_out, int out_size, void* d_ws, size_t ws_size,
                              hipStream_t stream) {
    const float* x    = (const float*)d_in[0];
    const int*   nidx = (const int*)d_in[1];
    const void*  maskp = d_in[2];
    const float* Wc = (const float*)d_in[3];
    const float* g0 = (const float*)d_in[4];
    const float* b0 = (const float*)d_in[5];
    const float* W1 = (const float*)d_in[6];
    const float* g1 = (const float*)d_in[7];
    const float* b1 = (const float*)d_in[8];
    const float* W2 = (const float*)d_in[9];
    const float* g2 = (const float*)d_in[10];
    const float* b2 = (const float*)d_in[11];

    char* ws = (char*)d_ws;
    unsigned short* out0 = (unsigned short*)ws;                    // (N+1)*32*2  = 6.40 MB
    unsigned short* out1 = (unsigned short*)(ws + 6400128);        // (N+1)*128*2 = 25.6 MB
    unsigned short* W1p  = (unsigned short*)(ws + 32000512);       // 221 KB
    unsigned short* W2p  = W1p + KOFF * 32 * 128;                  // 221 KB
    int* flagp = (int*)(W2p + KOFF * 128 * 32);

    repack_kernel<<<432, 256, 0, stream>>>(W1, W2, maskp, W1p, W2p, flagp, out0, out1);
    conv1_ln_gelu<<<NPTS / 8, 256, 0, stream>>>(x, Wc, g0, b0, out0);
    conv_k1<<<(NPTS + 63) / 64, 256, 0, stream>>>(nidx, maskp, flagp, out0, W1p, g1, b1, out1);
    conv_k2<<<(NPTS + 63) / 64, 256, 0, stream>>>(nidx, maskp, flagp, out1, W2p, g2, b2, x, (float*)d_out);
}

// Round 4
// 276.890 us; speedup vs baseline: 1.1349x; 1.1349x over previous
//
#include <hip/hip_runtime.h>
#include <hip/hip_bf16.h>
#include <math.h>

#define NPTS 100000
#define KOFF 27

typedef __attribute__((ext_vector_type(8))) __bf16 bf16x8;
typedef __attribute__((ext_vector_type(4))) float f32x4;

__device__ __forceinline__ unsigned short f2bf(float f) {
    unsigned int u = __float_as_uint(f);
    u += 0x7fffu + ((u >> 16) & 1u);   // RNE
    return (unsigned short)(u >> 16);
}

__device__ __forceinline__ float gelu_erf(float v) {
    return 0.5f * v * (1.0f + erff(v * 0.70710678118654752f));
}

// ---------------------------------------------------------------------------
// Kernel 0: repack W1/W2 (fp32 -> bf16) into per-lane MFMA B-fragment order,
// and sniff mask dtype (bool bytes vs int32) into *flagp.
// ---------------------------------------------------------------------------
__global__ __launch_bounds__(256)
void repack_kernel(const float* __restrict__ W1, const float* __restrict__ W2,
                   const void* __restrict__ maskp,
                   unsigned short* __restrict__ W1p,
                   unsigned short* __restrict__ W2p,
                   int* __restrict__ flagp) {
    int o = blockIdx.x * 256 + threadIdx.x;
    if (o == 0) {
        const unsigned int* mw = (const unsigned int*)maskp;
        int f = 0;
        for (int i = 0; i < 64; ++i) f |= (mw[i] > 1u) ? 1 : 0;
        *flagp = f;   // 1 => byte/bool mask, 0 => int32 mask
    }
    if (o < KOFF * 32 * 128) {
        int j = o & 7, lane = (o >> 3) & 63;
        int quad = lane >> 4, nn = lane & 15;
        int ct1 = (o >> 9) & 7, k1 = o >> 12;
        int kk1 = quad * 8 + j;
        W1p[o] = f2bf(W1[(k1 * 32 + kk1) * 128 + (ct1 * 16 + nn)]);
        int ct2 = (o >> 9) & 1, kc2 = (o >> 10) & 3, k2 = o >> 12;
        int kk2 = kc2 * 32 + quad * 8 + j;
        W2p[o] = f2bf(W2[(k2 * 128 + kk2) * 32 + (ct2 * 16 + nn)]);
    }
}

// ---------------------------------------------------------------------------
// Kernel 1: out0 = bf16( gelu( LN( x @ W_conv ) ) )   [N,32]
// ---------------------------------------------------------------------------
__global__ __launch_bounds__(256)
void conv1_ln_gelu(const float* __restrict__ x, const float* __restrict__ Wc,
                   const float* __restrict__ g0, const float* __restrict__ b0,
                   unsigned short* __restrict__ out0) {
    __shared__ float xs[256];
    __shared__ float wc[1024];
    int t = threadIdx.x;
    int nb = blockIdx.x * 8;
    xs[t] = x[nb * 32 + t];
    for (int i = t; i < 1024; i += 256) wc[i] = Wc[i];
    __syncthreads();
    int r = t >> 5, d = t & 31;
    const float* xr = &xs[r * 32];
    float v = 0.f;
#pragma unroll
    for (int c = 0; c < 32; ++c) v = fmaf(xr[c], wc[c * 32 + d], v);
    float s = v, s2 = v * v;
#pragma unroll
    for (int m = 16; m >= 1; m >>= 1) {
        s  += __shfl_xor(s,  m, 32);
        s2 += __shfl_xor(s2, m, 32);
    }
    float mu  = s * (1.f / 32.f);
    float var = s2 * (1.f / 32.f) - mu * mu;
    float y = (v - mu) * rsqrtf(var + 1e-6f) * g0[d] + b0[d];
    out0[nb * 32 + t] = f2bf(gelu_erf(y));
}

// ---------------------------------------------------------------------------
// Stage gather indices for 64 rows into LDS (-1 = masked/tail, skip load).
// Block = 64 threads (one wave).
// ---------------------------------------------------------------------------
__device__ __forceinline__ void stage_gidx64(int* s_gidx, const int* nidx,
                                             const void* maskp, int mflag,
                                             int nb, int t) {
    int cnt = (NPTS - nb < 64 ? NPTS - nb : 64) * KOFF;
    for (int i = t; i < 64 * KOFF; i += 64) {
        int g = -1;
        if (i < cnt) {
            int gi = nidx[nb * KOFF + i];
            int m = mflag ? (int)((const unsigned char*)maskp)[nb * KOFF + i]
                          : ((const int*)maskp)[nb * KOFF + i];
            g = m ? gi : -1;
        }
        s_gidx[i] = g;
    }
}

// ---------------------------------------------------------------------------
// Kernel 2: out1 = bf16( gelu( LN( sparse_conv(out0, W1) ) ) )   [N,128]
// 1 wave/block, 64 rows (4 row-tiles x 16), all 8 col-tiles.
// Depth-1 double-buffer rings for BOTH A (conditional gathers) and B.
// ---------------------------------------------------------------------------
__global__ __launch_bounds__(64, 2)
void conv_k1(const int* __restrict__ nidx, const void* __restrict__ maskp,
             const int* __restrict__ flagp,
             const unsigned short* __restrict__ out0,
             const unsigned short* __restrict__ W1p,
             const float* __restrict__ g1, const float* __restrict__ b1,
             unsigned short* __restrict__ out1) {
    __shared__ int s_gidx[64 * KOFF];

    int t = threadIdx.x;
    int nb = blockIdx.x * 64;
    int mflag = *flagp;
    stage_gidx64(s_gidx, nidx, maskp, mflag, nb, t);
    __syncthreads();

    int lane = t & 63;
    int mrow = lane & 15, quad = lane >> 4;
    const unsigned short* a_base = out0 + quad * 8;
    const int* gp0 = &s_gidx[(0 * 16 + mrow) * KOFF];
    const int* gp1 = &s_gidx[(1 * 16 + mrow) * KOFF];
    const int* gp2 = &s_gidx[(2 * 16 + mrow) * KOFF];
    const int* gp3 = &s_gidx[(3 * 16 + mrow) * KOFF];

    f32x4 acc[4][8] = {};
    bf16x8 a[2][4], b[2][8];

    // prologue: k=0 into slot 0
    {
        const unsigned short* wb = W1p + (lane << 3);
#pragma unroll
        for (int ct = 0; ct < 8; ++ct)
            b[0][ct] = *reinterpret_cast<const bf16x8*>(wb + ((ct * 64) << 3));
        int g0 = gp0[0], g1i = gp1[0], g2 = gp2[0], g3 = gp3[0];
        a[0][0] = bf16x8{}; if (g0  >= 0) a[0][0] = *reinterpret_cast<const bf16x8*>(a_base + g0  * 32);
        a[0][1] = bf16x8{}; if (g1i >= 0) a[0][1] = *reinterpret_cast<const bf16x8*>(a_base + g1i * 32);
        a[0][2] = bf16x8{}; if (g2  >= 0) a[0][2] = *reinterpret_cast<const bf16x8*>(a_base + g2  * 32);
        a[0][3] = bf16x8{}; if (g3  >= 0) a[0][3] = *reinterpret_cast<const bf16x8*>(a_base + g3  * 32);
    }

#pragma unroll
    for (int k = 0; k < KOFF; ++k) {
        int cur = k & 1, nxt = cur ^ 1;
        if (k + 1 < KOFF) {   // folds at compile time under full unroll
            const unsigned short* wb = W1p + ((((k + 1) * 8) * 64 + lane) << 3);
#pragma unroll
            for (int ct = 0; ct < 8; ++ct)
                b[nxt][ct] = *reinterpret_cast<const bf16x8*>(wb + ((ct * 64) << 3));
            int g0 = gp0[k + 1], g1i = gp1[k + 1], g2 = gp2[k + 1], g3 = gp3[k + 1];
            a[nxt][0] = bf16x8{}; if (g0  >= 0) a[nxt][0] = *reinterpret_cast<const bf16x8*>(a_base + g0  * 32);
            a[nxt][1] = bf16x8{}; if (g1i >= 0) a[nxt][1] = *reinterpret_cast<const bf16x8*>(a_base + g1i * 32);
            a[nxt][2] = bf16x8{}; if (g2  >= 0) a[nxt][2] = *reinterpret_cast<const bf16x8*>(a_base + g2  * 32);
            a[nxt][3] = bf16x8{}; if (g3  >= 0) a[nxt][3] = *reinterpret_cast<const bf16x8*>(a_base + g3  * 32);
        }
#pragma unroll
        for (int rt = 0; rt < 4; ++rt)
#pragma unroll
            for (int ct = 0; ct < 8; ++ct)
                acc[rt][ct] = __builtin_amdgcn_mfma_f32_16x16x32_bf16(a[cur][rt], b[cur][ct], acc[rt][ct], 0, 0, 0);
    }

    // Epilogue: LN(128) + GELU in-register; gamma/beta read direct (L2-hot).
    float gv[8], bv[8];
#pragma unroll
    for (int ct = 0; ct < 8; ++ct) {
        gv[ct] = g1[ct * 16 + mrow];
        bv[ct] = b1[ct * 16 + mrow];
    }
#pragma unroll
    for (int rt = 0; rt < 4; ++rt) {
        int n_base = nb + rt * 16 + quad * 4;
#pragma unroll
        for (int r = 0; r < 4; ++r) {
            float s = 0.f, s2 = 0.f;
#pragma unroll
            for (int ct = 0; ct < 8; ++ct) { float v = acc[rt][ct][r]; s += v; s2 += v * v; }
#pragma unroll
            for (int m = 1; m <= 8; m <<= 1) {
                s  += __shfl_xor(s,  m, 16);
                s2 += __shfl_xor(s2, m, 16);
            }
            float mu = s * (1.f / 128.f);
            float rs = rsqrtf(s2 * (1.f / 128.f) - mu * mu + 1e-6f);
            int n = n_base + r;
            if (n < NPTS) {
#pragma unroll
                for (int ct = 0; ct < 8; ++ct) {
                    float y = (acc[rt][ct][r] - mu) * rs * gv[ct] + bv[ct];
                    out1[n * 128 + ct * 16 + mrow] = f2bf(gelu_erf(y));
                }
            }
        }
    }
}

// ---------------------------------------------------------------------------
// Kernel 3: out = gelu( LN( sparse_conv(out1, W2) ) + x )   [N,32] fp32
// 1 wave/block, 64 rows (4 row-tiles), 2 col-tiles, K=128 (4 kc chunks).
// Depth-1 rings for A (conditional, 4x16B per row) and B.
// ---------------------------------------------------------------------------
__global__ __launch_bounds__(64, 2)
void conv_k2(const int* __restrict__ nidx, const void* __restrict__ maskp,
             const int* __restrict__ flagp,
             const unsigned short* __restrict__ out1,
             const unsigned short* __restrict__ W2p,
             const float* __restrict__ g2, const float* __restrict__ b2,
             const float* __restrict__ x, float* __restrict__ outp) {
    __shared__ int s_gidx[64 * KOFF];

    int t = threadIdx.x;
    int nb = blockIdx.x * 64;
    int mflag = *flagp;
    stage_gidx64(s_gidx, nidx, maskp, mflag, nb, t);
    __syncthreads();

    int lane = t & 63;
    int mrow = lane & 15, quad = lane >> 4;
    const unsigned short* a_base = out1 + quad * 8;
    const int* gp0 = &s_gidx[(0 * 16 + mrow) * KOFF];
    const int* gp1 = &s_gidx[(1 * 16 + mrow) * KOFF];
    const int* gp2 = &s_gidx[(2 * 16 + mrow) * KOFF];
    const int* gp3 = &s_gidx[(3 * 16 + mrow) * KOFF];

    f32x4 acc[4][2] = {};
    bf16x8 a[2][4][4], b[2][8];

    // prologue: k=0 into slot 0
    {
        const unsigned short* wb = W2p + (lane << 3);
#pragma unroll
        for (int f = 0; f < 8; ++f)
            b[0][f] = *reinterpret_cast<const bf16x8*>(wb + ((f * 64) << 3));
        int gg[4] = { gp0[0], gp1[0], gp2[0], gp3[0] };
#pragma unroll
        for (int rt = 0; rt < 4; ++rt) {
#pragma unroll
            for (int kc = 0; kc < 4; ++kc) a[0][rt][kc] = bf16x8{};
            if (gg[rt] >= 0) {
#pragma unroll
                for (int kc = 0; kc < 4; ++kc)
                    a[0][rt][kc] = *reinterpret_cast<const bf16x8*>(a_base + gg[rt] * 128 + kc * 32);
            }
        }
    }

#pragma unroll
    for (int k = 0; k < KOFF; ++k) {
        int cur = k & 1, nxt = cur ^ 1;
        if (k + 1 < KOFF) {
            const unsigned short* wb = W2p + ((((k + 1) * 8) * 64 + lane) << 3);
#pragma unroll
            for (int f = 0; f < 8; ++f)
                b[nxt][f] = *reinterpret_cast<const bf16x8*>(wb + ((f * 64) << 3));
            int gg[4] = { gp0[k + 1], gp1[k + 1], gp2[k + 1], gp3[k + 1] };
#pragma unroll
            for (int rt = 0; rt < 4; ++rt) {
#pragma unroll
                for (int kc = 0; kc < 4; ++kc) a[nxt][rt][kc] = bf16x8{};
                if (gg[rt] >= 0) {
#pragma unroll
                    for (int kc = 0; kc < 4; ++kc)
                        a[nxt][rt][kc] = *reinterpret_cast<const bf16x8*>(a_base + gg[rt] * 128 + kc * 32);
                }
            }
        }
#pragma unroll
        for (int rt = 0; rt < 4; ++rt)
#pragma unroll
            for (int kc = 0; kc < 4; ++kc) {
                acc[rt][0] = __builtin_amdgcn_mfma_f32_16x16x32_bf16(a[cur][rt][kc], b[cur][kc * 2 + 0], acc[rt][0], 0, 0, 0);
                acc[rt][1] = __builtin_amdgcn_mfma_f32_16x16x32_bf16(a[cur][rt][kc], b[cur][kc * 2 + 1], acc[rt][1], 0, 0, 0);
            }
    }

    // Epilogue: LN(32) + residual + GELU in-register.
    float gv0 = g2[mrow], gv1 = g2[mrow + 16];
    float bv0 = b2[mrow], bv1 = b2[mrow + 16];
#pragma unroll
    for (int rt = 0; rt < 4; ++rt) {
        int n_base = nb + rt * 16 + quad * 4;
#pragma unroll
        for (int r = 0; r < 4; ++r) {
            float v0 = acc[rt][0][r], v1 = acc[rt][1][r];
            float s = v0 + v1, s2 = v0 * v0 + v1 * v1;
#pragma unroll
            for (int m = 1; m <= 8; m <<= 1) {
                s  += __shfl_xor(s,  m, 16);
                s2 += __shfl_xor(s2, m, 16);
            }
            float mu = s * (1.f / 32.f);
            float rs = rsqrtf(s2 * (1.f / 32.f) - mu * mu + 1e-6f);
            int n = n_base + r;
            if (n < NPTS) {
                float y0 = (v0 - mu) * rs * gv0 + bv0 + x[n * 32 + mrow];
                float y1 = (v1 - mu) * rs * gv1 + bv1 + x[n * 32 + mrow + 16];
                outp[n * 32 + mrow]      = gelu_erf(y0);
                outp[n * 32 + mrow + 16] = gelu_erf(y1);
            }
        }
    }
}

// ---------------------------------------------------------------------------
extern "C" void kernel_launch(void* const* d_in, const int* in_sizes, int n_in,
                              void* d_out, int out_size, void* d_ws, size_t ws_size,
                              hipStream_t stream) {
    const float* x    = (const float*)d_in[0];
    const int*   nidx = (const int*)d_in[1];
    const void*  maskp = d_in[2];
    const float* Wc = (const float*)d_in[3];
    const float* g0 = (const float*)d_in[4];
    const float* b0 = (const float*)d_in[5];
    const float* W1 = (const float*)d_in[6];
    const float* g1 = (const float*)d_in[7];
    const float* b1 = (const float*)d_in[8];
    const float* W2 = (const float*)d_in[9];
    const float* g2 = (const float*)d_in[10];
    const float* b2 = (const float*)d_in[11];

    char* ws = (char*)d_ws;
    unsigned short* out0 = (unsigned short*)ws;                    // 6.4 MB
    unsigned short* out1 = (unsigned short*)(ws + 6400000);        // 25.6 MB
    unsigned short* W1p  = (unsigned short*)(ws + 32000000);       // 221 KB
    unsigned short* W2p  = W1p + KOFF * 32 * 128;                  // 221 KB
    int* flagp = (int*)(W2p + KOFF * 128 * 32);

    repack_kernel<<<432, 256, 0, stream>>>(W1, W2, maskp, W1p, W2p, flagp);
    conv1_ln_gelu<<<NPTS / 8, 256, 0, stream>>>(x, Wc, g0, b0, out0);
    conv_k1<<<(NPTS + 63) / 64, 64, 0, stream>>>(nidx, maskp, flagp, out0, W1p, g1, b1, out1);
    conv_k2<<<(NPTS + 63) / 64, 64, 0, stream>>>(nidx, maskp, flagp, out1, W2p, g2, b2, x, (float*)d_out);
}